// Round 1
// baseline (1067.779 us; speedup 1.0000x reference)
//
#include <hip/hip_runtime.h>
#include <math.h>

#define N_NODES 50000
#define N_EDGES 1600000
#define N_GRAPH 500

// ---------- helpers ----------
__device__ __forceinline__ unsigned f2u_ord(float f) {
    unsigned b = __float_as_uint(f);
    return (b & 0x80000000u) ? ~b : (b | 0x80000000u);
}
__device__ __forceinline__ float u2f_ord(unsigned u) {
    return __uint_as_float((u & 0x80000000u) ? (u ^ 0x80000000u) : ~u);
}

// ---------- CSR build ----------
__global__ void hist_kernel(const int* __restrict__ dst, int* __restrict__ deg, int E) {
    int e = blockIdx.x * blockDim.x + threadIdx.x;
    if (e < E) atomicAdd(&deg[dst[e]], 1);
}

__global__ void scan_kernel(const int* __restrict__ deg, int* __restrict__ rowptr,
                            int* __restrict__ cursor, int N) {
    __shared__ int part[1024];
    int t = threadIdx.x;
    int chunk = (N + 1023) / 1024;
    int lo = t * chunk;
    int hi = min(lo + chunk, N);
    int s = 0;
    for (int i = lo; i < hi; i++) s += deg[i];
    part[t] = s;
    __syncthreads();
    // Hillis-Steele inclusive scan
    for (int off = 1; off < 1024; off <<= 1) {
        int add = (t >= off) ? part[t - off] : 0;
        __syncthreads();
        part[t] += add;
        __syncthreads();
    }
    int run = (t == 0) ? 0 : part[t - 1];
    for (int i = lo; i < hi; i++) {
        rowptr[i] = run;
        cursor[i] = run;
        run += deg[i];
    }
    if (t == 1023) rowptr[N] = part[1023];
}

__global__ void fill_kernel(const int* __restrict__ src, const int* __restrict__ dst,
                            int* __restrict__ cursor, int* __restrict__ csr_src, int E) {
    int e = blockIdx.x * blockDim.x + threadIdx.x;
    if (e < E) {
        int d = dst[e];
        int pos = atomicAdd(&cursor[d], 1);
        csr_src[pos] = src[e];
    }
}

// ---------- aggregation: u[d] = h[d] + sum_{e: dst=d} h[src_e] ----------
template <int DFEAT>
__global__ __launch_bounds__(256) void agg_kernel(const float* __restrict__ h,
                                                  const int* __restrict__ rowptr,
                                                  const int* __restrict__ csr_src,
                                                  float* __restrict__ u, int N) {
    int wid = (blockIdx.x * blockDim.x + threadIdx.x) >> 6;
    int lane = threadIdx.x & 63;
    if (wid >= N) return;
    int start = rowptr[wid];
    int end = rowptr[wid + 1];
    float acc0 = h[(size_t)wid * DFEAT + lane];
    float acc1 = 0.f;
    if (DFEAT == 128) acc1 = h[(size_t)wid * DFEAT + 64 + lane];
    for (int j = start; j < end; j++) {
        int s = csr_src[j];
        acc0 += h[(size_t)s * DFEAT + lane];
        if (DFEAT == 128) acc1 += h[(size_t)s * DFEAT + 64 + lane];
    }
    u[(size_t)wid * DFEAT + lane] = acc0;
    if (DFEAT == 128) u[(size_t)wid * DFEAT + 64 + lane] = acc1;
}

// ---------- fused MLP per layer:
//  t = relu(u @ W1 + b1); h = t @ W2 + b2; (relu if not last)
//  score[row] (=/+)= h . Wm[layer*64 : layer*64+64]
template <int DIN, bool RELU_OUT, int LAYER>
__global__ __launch_bounds__(256) void mlp_kernel(const float* __restrict__ u,
                                                  const float* __restrict__ W1,
                                                  const float* __restrict__ b1,
                                                  const float* __restrict__ W2,
                                                  const float* __restrict__ b2,
                                                  const float* __restrict__ Wm,
                                                  float* __restrict__ hout,
                                                  float* __restrict__ score, int N) {
    __shared__ float sW1[DIN * 64];
    __shared__ float sW2[64 * 64];
    __shared__ float sb1[64], sb2[64], sWm[64];
    __shared__ float su[4][DIN];
    __shared__ float st[4][64];
    int tid = threadIdx.x;
    for (int i = tid; i < DIN * 64; i += 256) sW1[i] = W1[i];
    for (int i = tid; i < 64 * 64; i += 256) sW2[i] = W2[i];
    if (tid < 64) {
        sb1[tid] = b1[tid];
        sb2[tid] = b2[tid];
        sWm[tid] = Wm[LAYER * 64 + tid];
    }
    int wv = tid >> 6;
    int lane = tid & 63;
    int row = blockIdx.x * 4 + wv;
    int rowc = min(row, N - 1);
    bool active = (row < N);

    su[wv][lane] = u[(size_t)rowc * DIN + lane];
    if (DIN == 128) su[wv][64 + lane] = u[(size_t)rowc * DIN + 64 + lane];
    __syncthreads();

    float acc = sb1[lane];
#pragma unroll 8
    for (int k = 0; k < DIN; k++) acc = fmaf(su[wv][k], sW1[k * 64 + lane], acc);
    float t = fmaxf(acc, 0.f);
    st[wv][lane] = t;
    __syncthreads();

    float acc2 = sb2[lane];
#pragma unroll 8
    for (int k = 0; k < 64; k++) acc2 = fmaf(st[wv][k], sW2[k * 64 + lane], acc2);
    float hv = RELU_OUT ? fmaxf(acc2, 0.f) : acc2;

    float p = hv * sWm[lane];
#pragma unroll
    for (int m = 32; m >= 1; m >>= 1) p += __shfl_xor(p, m);

    if (active) {
        hout[(size_t)row * 64 + lane] = hv;
        if (lane == 0) {
            if (LAYER == 0) score[row] = p;
            else score[row] += p;
        }
    }
}

// ---------- edge softmax + new_score, per dst node ----------
__global__ __launch_bounds__(256) void edge_softmax_kernel(const float* __restrict__ score,
                                                           const int* __restrict__ rowptr,
                                                           const int* __restrict__ csr_src,
                                                           const float* __restrict__ bm,
                                                           float* __restrict__ nsf, int N) {
    int wid = (blockIdx.x * blockDim.x + threadIdx.x) >> 6;
    int lane = threadIdx.x & 63;
    if (wid >= N) return;
    float b = bm[0];
    float sd = score[wid] + b;
    int start = rowptr[wid];
    int end = rowptr[wid + 1];
    float m = -INFINITY;
    for (int j = start + lane; j < end; j += 64) {
        float ss = score[csr_src[j]] + b;
        m = fmaxf(m, ss * sd);
    }
#pragma unroll
    for (int o = 32; o >= 1; o >>= 1) m = fmaxf(m, __shfl_xor(m, o));
    float se = 0.f, swe = 0.f;
    if (m > -INFINITY) {
        for (int j = start + lane; j < end; j += 64) {
            float ss = score[csr_src[j]] + b;
            float e = expf(ss * sd - m);
            se += e;
            swe += ss * e;
        }
#pragma unroll
        for (int o = 32; o >= 1; o >>= 1) {
            se += __shfl_xor(se, o);
            swe += __shfl_xor(swe, o);
        }
    }
    float ns = (se > 0.f) ? (swe / se) : 0.f;
    if (lane == 0) nsf[wid] = sd + ns;
}

// ---------- graph-segment softmax ----------
__global__ void gmax_kernel(const float* __restrict__ nsf, const int* __restrict__ batch,
                            unsigned* __restrict__ gmaxu, int N) {
    int i = blockIdx.x * blockDim.x + threadIdx.x;
    if (i < N) atomicMax(&gmaxu[batch[i]], f2u_ord(nsf[i]));
}
__global__ void gexp_kernel(const float* __restrict__ nsf, const int* __restrict__ batch,
                            const unsigned* __restrict__ gmaxu, float* __restrict__ gsum,
                            float* __restrict__ out, int N) {
    int i = blockIdx.x * blockDim.x + threadIdx.x;
    if (i < N) {
        int b = batch[i];
        float m = u2f_ord(gmaxu[b]);
        float e = expf(nsf[i] - m);
        out[i] = e;
        atomicAdd(&gsum[b], e);
    }
}
__global__ void gdiv_kernel(const int* __restrict__ batch, const float* __restrict__ gsum,
                            float* __restrict__ out, int N) {
    int i = blockIdx.x * blockDim.x + threadIdx.x;
    if (i < N) out[i] /= gsum[batch[i]];
}

extern "C" void kernel_launch(void* const* d_in, const int* in_sizes, int n_in,
                              void* d_out, int out_size, void* d_ws, size_t ws_size,
                              hipStream_t stream) {
    const int N = N_NODES, E = N_EDGES, G = N_GRAPH;

    const float* x = (const float*)d_in[0];
    const int* ei = (const int*)d_in[1];
    const int* batch = (const int*)d_in[2];
    const float* W1a[3] = {(const float*)d_in[3], (const float*)d_in[7], (const float*)d_in[11]};
    const float* b1a[3] = {(const float*)d_in[4], (const float*)d_in[8], (const float*)d_in[12]};
    const float* W2a[3] = {(const float*)d_in[5], (const float*)d_in[9], (const float*)d_in[13]};
    const float* b2a[3] = {(const float*)d_in[6], (const float*)d_in[10], (const float*)d_in[14]};
    const float* Wm = (const float*)d_in[15];
    const float* bm = (const float*)d_in[16];
    float* out = (float*)d_out;

    const int* srcp = ei;
    const int* dstp = ei + E;

    // workspace layout (~59 MB)
    float* u = (float*)d_ws;                    // N*128
    float* hA = u + (size_t)N * 128;            // N*64
    float* hB = hA + (size_t)N * 64;            // N*64
    float* score = hB + (size_t)N * 64;         // N
    float* nsf = score + N;                     // N
    float* gsum = nsf + N;                      // G
    unsigned* gmaxu = (unsigned*)(gsum + G);    // G
    int* deg = (int*)(gmaxu + G);               // N
    int* rowptr = deg + N;                      // N+1
    int* cursor = rowptr + N + 1;               // N
    int* csr_src = cursor + N;                  // E

    hipMemsetAsync(deg, 0, sizeof(int) * N, stream);
    hipMemsetAsync(gmaxu, 0, sizeof(unsigned) * G, stream);
    hipMemsetAsync(gsum, 0, sizeof(float) * G, stream);

    hist_kernel<<<E / 256, 256, 0, stream>>>(dstp, deg, E);
    scan_kernel<<<1, 1024, 0, stream>>>(deg, rowptr, cursor, N);
    fill_kernel<<<E / 256, 256, 0, stream>>>(srcp, dstp, cursor, csr_src, E);

    int nodeBlocks = N / 4;  // 4 waves per block, one wave per node/row
    agg_kernel<128><<<nodeBlocks, 256, 0, stream>>>(x, rowptr, csr_src, u, N);
    mlp_kernel<128, true, 0><<<nodeBlocks, 256, 0, stream>>>(u, W1a[0], b1a[0], W2a[0], b2a[0], Wm, hA, score, N);
    agg_kernel<64><<<nodeBlocks, 256, 0, stream>>>(hA, rowptr, csr_src, u, N);
    mlp_kernel<64, true, 1><<<nodeBlocks, 256, 0, stream>>>(u, W1a[1], b1a[1], W2a[1], b2a[1], Wm, hB, score, N);
    agg_kernel<64><<<nodeBlocks, 256, 0, stream>>>(hB, rowptr, csr_src, u, N);
    mlp_kernel<64, false, 2><<<nodeBlocks, 256, 0, stream>>>(u, W1a[2], b1a[2], W2a[2], b2a[2], Wm, hA, score, N);

    edge_softmax_kernel<<<nodeBlocks, 256, 0, stream>>>(score, rowptr, csr_src, bm, nsf, N);

    int nb = (N + 255) / 256;
    gmax_kernel<<<nb, 256, 0, stream>>>(nsf, batch, gmaxu, N);
    gexp_kernel<<<nb, 256, 0, stream>>>(nsf, batch, gmaxu, gsum, out, N);
    gdiv_kernel<<<nb, 256, 0, stream>>>(batch, gsum, out, N);
}